// Round 1
// baseline (322.271 us; speedup 1.0000x reference)
//
#include <hip/hip_runtime.h>
#include <math.h>

#define NN 13
#define BB 64
#define SS 128
#define HH 768
#define DD 512

__device__ __forceinline__ float gelu_f(float x) {
    return 0.5f * x * (1.0f + erff(x * 0.7071067811865475f));
}

__device__ __forceinline__ int shape_hash(const int* __restrict__ active,
                                          const int* __restrict__ is_leaf, int b) {
    unsigned long long acc = 0ull, w = 1ull;
    for (int i = 0; i < NN; ++i) {
        unsigned long long p = (unsigned long long)(active[b*NN + i] * 2 + is_leaf[b*NN + i]);
        acc += p * w;
        w *= 31ull;
    }
    long long h = (long long)acc;
    if (h < 0) h = -h;
    return (int)(h % 256);
}

// One block per (node n, batch b) pair, R = n*64 + b. Only leaf rows computed.
__global__ __launch_bounds__(256)
void pool_kernel(const float* __restrict__ ls, const int* __restrict__ masks,
                 const int* __restrict__ is_leaf, float* __restrict__ pooled)
{
    int R = blockIdx.x;
    int n = R >> 6, b = R & 63;
    if (!is_leaf[b*NN + n]) return;
    const float* src = ls + (size_t)(b*NN + n) * SS * HH;
    const int* mk = masks + (b*NN + n) * SS;
    int t = threadIdx.x;

    __shared__ float lsm[SS];
    if (t < SS) lsm[t] = (float)mk[t];
    __syncthreads();

    float s0 = 0.f, s1 = 0.f, s2 = 0.f, cnt = 0.f;
    #pragma unroll 4
    for (int s = 0; s < SS; ++s) {
        float m = lsm[s];
        const float* row = src + (size_t)s * HH + t;
        s0 += m * row[0];
        s1 += m * row[256];
        s2 += m * row[512];
        cnt += m;
    }
    float inv = 1.f / fmaxf(cnt, 1.f);
    float* dst = pooled + (size_t)R * HH + t;
    dst[0]   = s0 * inv;
    dst[256] = s1 * inv;
    dst[512] = s2 * inv;
}

enum { LEAF_G1 = 0, LEAF_G2 = 1, MERGE_G1 = 2, MERGE_G2 = 3, FINAL_G2 = 4 };

// Generic f32 SIMT GEMM: M-tile = 64 rows (one node, all batches), N-tile = 32.
// 256 threads, each computes 2x4 micro-tile. BK = 32.
template<int MODE>
__global__ __launch_bounds__(256)
void gemm_k(const float* __restrict__ A, const float* __restrict__ W,
            const float* __restrict__ bias,
            float* __restrict__ Cout,
            const int* __restrict__ is_leaf, const int* __restrict__ active,
            const int* __restrict__ depth, const int* __restrict__ left,
            const int* __restrict__ right,
            const float* __restrict__ depth_emb, const float* __restrict__ shape_emb,
            const float* __restrict__ noderep,
            int K, int n0, int n1, int n2)
{
    __shared__ __align__(16) float lsA[32][66];  // [k][r], padded stride 66
    __shared__ __align__(16) float lsB[32][36];  // [k][c], padded stride 36

    const int tid = threadIdx.x;
    const int bx = blockIdx.x;   // N tile (0..15)
    const int by = blockIdx.y;   // node (leaf modes) or level slot (merge modes)
    const int j0 = bx * 32;

    int node = 0, lc = 0, rc = 0;
    if (MODE == LEAF_G1 || MODE == LEAF_G2) {
        node = by;
        bool anyleaf = false;
        for (int b2 = 0; b2 < BB; ++b2)
            anyleaf = anyleaf || (is_leaf[b2*NN + node] != 0);
        if (!anyleaf) return;   // node_repr stays 0 there (memset)
    } else {
        node = (by == 0) ? n0 : ((by == 1) ? n1 : n2);
        if (MODE == MERGE_G1) { lc = left[node]; rc = right[node]; }
    }

    const int tx = tid & 7, ty = tid >> 3;
    float acc[2][4] = {{0,0,0,0},{0,0,0,0}};

    for (int k0 = 0; k0 < K; k0 += 32) {
        #pragma unroll
        for (int i = 0; i < 8; ++i) {           // stage A: 64x32
            int e = i*256 + tid;
            int r = e >> 5, k = e & 31;
            float v;
            if (MODE == LEAF_G1) {
                v = is_leaf[r*NN + node] ? A[(size_t)(node*64 + r)*HH + k0 + k] : 0.f;
            } else if (MODE == LEAF_G2) {
                v = A[(size_t)(node*64 + r)*DD + k0 + k];
            } else if (MODE == MERGE_G1) {
                int kg = k0 + k;
                v = (kg < DD) ? noderep[(size_t)(lc*64 + r)*DD + kg]
                              : noderep[(size_t)(rc*64 + r)*DD + (kg - DD)];
            } else {  // MERGE_G2 / FINAL_G2: A = mhid, indexed by slot
                v = A[(size_t)(by*64 + r)*DD + k0 + k];
            }
            lsA[k][r] = v;
        }
        #pragma unroll
        for (int i = 0; i < 4; ++i) {           // stage B: 32x32
            int e = i*256 + tid;
            int kr = e >> 5, c = e & 31;
            lsB[kr][c] = W[(size_t)(k0 + kr)*DD + j0 + c];
        }
        __syncthreads();
        #pragma unroll
        for (int kk = 0; kk < 32; ++kk) {
            float2 a2 = *(const float2*)&lsA[kk][2*ty];
            float4 b4 = *(const float4*)&lsB[kk][tx*4];
            acc[0][0] += a2.x * b4.x; acc[0][1] += a2.x * b4.y;
            acc[0][2] += a2.x * b4.z; acc[0][3] += a2.x * b4.w;
            acc[1][0] += a2.y * b4.x; acc[1][1] += a2.y * b4.y;
            acc[1][2] += a2.y * b4.z; acc[1][3] += a2.y * b4.w;
        }
        __syncthreads();
    }

    const int r0 = 2*ty, r1 = r0 + 1;

    if (MODE == LEAF_G1) {
        float* dst = Cout + (size_t)(node*64)*DD;
        #pragma unroll
        for (int j = 0; j < 4; ++j) {
            int jc = j0 + tx*4 + j;
            dst[(size_t)r0*DD + jc] = gelu_f(acc[0][j] + bias[jc]);
            dst[(size_t)r1*DD + jc] = gelu_f(acc[1][j] + bias[jc]);
        }
    } else if (MODE == LEAF_G2) {
        int dp = depth[node];
        const float* de = depth_emb + (size_t)dp*DD;
        bool lf0 = is_leaf[r0*NN + node] != 0;
        bool lf1 = is_leaf[r1*NN + node] != 0;
        float* dst = Cout + (size_t)(node*64)*DD;
        #pragma unroll
        for (int j = 0; j < 4; ++j) {
            int jc = j0 + tx*4 + j;
            if (lf0) dst[(size_t)r0*DD + jc] = acc[0][j] + bias[jc] + de[jc];
            if (lf1) dst[(size_t)r1*DD + jc] = acc[1][j] + bias[jc] + de[jc];
        }
    } else if (MODE == MERGE_G1) {
        float* dst = Cout + (size_t)(by*64)*DD;   // mhid, indexed by slot
        #pragma unroll
        for (int j = 0; j < 4; ++j) {
            int jc = j0 + tx*4 + j;
            dst[(size_t)r0*DD + jc] = gelu_f(acc[0][j] + bias[jc]);
            dst[(size_t)r1*DD + jc] = gelu_f(acc[1][j] + bias[jc]);
        }
    } else {
        int dp = depth[node];
        const float* de = depth_emb + (size_t)dp*DD;
        bool anyInt = false;
        for (int b2 = 0; b2 < BB; ++b2)
            anyInt = anyInt || (active[b2*NN + node] && !is_leaf[b2*NN + node]);
        bool i0 = active[r0*NN + node] && !is_leaf[r0*NN + node];
        bool i1 = active[r1*NN + node] && !is_leaf[r1*NN + node];
        const float* nrep = noderep + (size_t)(node*64)*DD;
        if (MODE == MERGE_G2) {
            float* dst = Cout + (size_t)(node*64)*DD;   // node_repr column
            #pragma unroll
            for (int j = 0; j < 4; ++j) {
                int jc = j0 + tx*4 + j;
                float m0 = acc[0][j] + bias[jc] + de[jc];
                float m1 = acc[1][j] + bias[jc] + de[jc];
                float c0 = anyInt ? (i0 ? m0 : 0.f) : nrep[(size_t)r0*DD + jc];
                float c1 = anyInt ? (i1 ? m1 : 0.f) : nrep[(size_t)r1*DD + jc];
                dst[(size_t)r0*DD + jc] = c0;
                dst[(size_t)r1*DD + jc] = c1;
            }
        } else {  // FINAL_G2: node 0 column + shape_emb -> out
            int h0 = shape_hash(active, is_leaf, r0);
            int h1 = shape_hash(active, is_leaf, r1);
            #pragma unroll
            for (int j = 0; j < 4; ++j) {
                int jc = j0 + tx*4 + j;
                float m0 = acc[0][j] + bias[jc] + de[jc];
                float m1 = acc[1][j] + bias[jc] + de[jc];
                float c0 = anyInt ? (i0 ? m0 : 0.f) : nrep[(size_t)r0*DD + jc];
                float c1 = anyInt ? (i1 ? m1 : 0.f) : nrep[(size_t)r1*DD + jc];
                Cout[(size_t)r0*DD + jc] = c0 + shape_emb[(size_t)h0*DD + jc];
                Cout[(size_t)r1*DD + jc] = c1 + shape_emb[(size_t)h1*DD + jc];
            }
        }
    }
}

extern "C" void kernel_launch(void* const* d_in, const int* in_sizes, int n_in,
                              void* d_out, int out_size, void* d_ws, size_t ws_size,
                              hipStream_t stream)
{
    const int*   is_leaf     = (const int*)d_in[0];
    const int*   active      = (const int*)d_in[1];
    const int*   depth       = (const int*)d_in[2];
    const int*   left        = (const int*)d_in[3];
    const int*   right       = (const int*)d_in[4];
    const float* leaf_states = (const float*)d_in[5];
    const int*   leaf_masks  = (const int*)d_in[6];
    const float* Wl1 = (const float*)d_in[7];
    const float* bl1 = (const float*)d_in[8];
    const float* Wl2 = (const float*)d_in[9];
    const float* bl2 = (const float*)d_in[10];
    const float* Wm1 = (const float*)d_in[11];
    const float* bm1 = (const float*)d_in[12];
    const float* Wm2 = (const float*)d_in[13];
    const float* bm2 = (const float*)d_in[14];
    const float* depth_emb = (const float*)d_in[15];
    const float* shape_emb = (const float*)d_in[16];
    float* out = (float*)d_out;
    float* ws  = (float*)d_ws;

    // ws layout (floats), node-major rows R = n*64 + b
    float* pooled  = ws;                       // 832*768
    float* hidden  = pooled + 832*768;         // 832*512
    float* noderep = hidden + 832*512;         // 832*512
    float* mhid    = noderep + 832*512;        // 3*64*512

    hipMemsetAsync(noderep, 0, (size_t)832*512*sizeof(float), stream);

    pool_kernel<<<832, 256, 0, stream>>>(leaf_states, leaf_masks, is_leaf, pooled);

    // leaf MLP over all nodes (inactive node-tiles exit immediately)
    gemm_k<LEAF_G1><<<dim3(16, 13), 256, 0, stream>>>(
        pooled, Wl1, bl1, hidden, is_leaf, active, depth, left, right,
        depth_emb, shape_emb, noderep, HH, 0, 0, 0);
    gemm_k<LEAF_G2><<<dim3(16, 13), 256, 0, stream>>>(
        hidden, Wl2, bl2, noderep, is_leaf, active, depth, left, right,
        depth_emb, shape_emb, noderep, DD, 0, 0, 0);

    // merge level 1: nodes {3,4,5}
    gemm_k<MERGE_G1><<<dim3(16, 3), 256, 0, stream>>>(
        mhid, Wm1, bm1, mhid, is_leaf, active, depth, left, right,
        depth_emb, shape_emb, noderep, 2*DD, 3, 4, 5);
    gemm_k<MERGE_G2><<<dim3(16, 3), 256, 0, stream>>>(
        mhid, Wm2, bm2, noderep, is_leaf, active, depth, left, right,
        depth_emb, shape_emb, noderep, DD, 3, 4, 5);

    // merge level 2: nodes {1,2}
    gemm_k<MERGE_G1><<<dim3(16, 2), 256, 0, stream>>>(
        mhid, Wm1, bm1, mhid, is_leaf, active, depth, left, right,
        depth_emb, shape_emb, noderep, 2*DD, 1, 2, 0);
    gemm_k<MERGE_G2><<<dim3(16, 2), 256, 0, stream>>>(
        mhid, Wm2, bm2, noderep, is_leaf, active, depth, left, right,
        depth_emb, shape_emb, noderep, DD, 1, 2, 0);

    // merge level 3: node {0} -> fused hash + shape_emb + output
    gemm_k<MERGE_G1><<<dim3(16, 1), 256, 0, stream>>>(
        mhid, Wm1, bm1, mhid, is_leaf, active, depth, left, right,
        depth_emb, shape_emb, noderep, 2*DD, 0, 0, 0);
    gemm_k<FINAL_G2><<<dim3(16, 1), 256, 0, stream>>>(
        mhid, Wm2, bm2, out, is_leaf, active, depth, left, right,
        depth_emb, shape_emb, noderep, DD, 0, 0, 0);
}